// Round 1
// baseline (1333.342 us; speedup 1.0000x reference)
//
#include <hip/hip_runtime.h>
#include <math.h>

#define NNODES 100000
#define NSUB   65536
#define NEDGE  655360
#define NBATCH 4096

#define BK  32
#define LDT 68   // padded leading dim for k-major LDS tiles (mult of 4)

__device__ __forceinline__ unsigned short f2bf(float x) {
  unsigned int b = __float_as_uint(x);
  b += 0x7fffu + ((b >> 16) & 1u);           // RNE
  return (unsigned short)(b >> 16);
}
__device__ __forceinline__ float bf2f(unsigned short u) {
  return __uint_as_float(((unsigned int)u) << 16);
}

__global__ void k_sentinel(float* out) { out[0] = -12345.0f; }

__global__ void k_pack(const float* __restrict__ Wq, const float* __restrict__ bq,
                       const float* __restrict__ Wk, const float* __restrict__ bk,
                       const float* __restrict__ Wv, const float* __restrict__ bv,
                       const float* __restrict__ Ws, const float* __restrict__ bs,
                       float* __restrict__ Wcat, float* __restrict__ bcat) {
  int idx = blockIdx.x * 256 + threadIdx.x;
  if (idx < 256 * 512) {
    int k = idx >> 9, c = idx & 511;
    int g = c >> 7, cc = c & 127;
    const float* W = (g == 0) ? Wq : (g == 1) ? Wk : (g == 2) ? Wv : Ws;
    Wcat[idx] = W[k * 128 + cc];
  } else if (idx < 256 * 512 + 512) {
    int c = idx - 256 * 512;
    int g = c >> 7, cc = c & 127;
    const float* bsrc = (g == 0) ? bq : (g == 1) ? bk : (g == 2) ? bv : bs;
    bcat[c] = bsrc[cc];
  }
}

__global__ void k_assoc(const int* __restrict__ n_id, int* __restrict__ assoc) {
  int i = blockIdx.x * 256 + threadIdx.x;
  if (i < NSUB) assoc[n_id[i]] = i;
}

__global__ void k_relt(const int* __restrict__ edge_index, const int* __restrict__ n_id,
                       const float* __restrict__ last_update, const float* __restrict__ edge_t,
                       float* __restrict__ rel_t) {
  int e = blockIdx.x * 256 + threadIdx.x;
  if (e < NEDGE) {
    int se = edge_index[e];
    rel_t[e] = last_update[n_id[se]] - edge_t[e];
  }
}

__global__ void k_deg(const int* __restrict__ edge_index, int* __restrict__ deg) {
  int e = blockIdx.x * 256 + threadIdx.x;
  if (e < NEDGE) atomicAdd(&deg[edge_index[NEDGE + e]], 1);
}

__global__ __launch_bounds__(1024)
void k_scan(const int* __restrict__ deg, int* __restrict__ offs, int* __restrict__ cursor) {
  __shared__ int wsum[16];
  __shared__ int carry_s;
  int t = threadIdx.x, w = t >> 6, l = t & 63;
  if (t == 0) carry_s = 0;
  __syncthreads();
  for (int base = 0; base < NSUB; base += 1024) {
    int i = base + t;
    int v = deg[i];
    int s = v;
    #pragma unroll
    for (int d = 1; d < 64; d <<= 1) {
      int u = __shfl_up(s, d, 64);
      if (l >= d) s += u;
    }
    if (l == 63) wsum[w] = s;
    __syncthreads();
    int woff = 0;
    for (int k2 = 0; k2 < w; k2++) woff += wsum[k2];
    int total = 0;
    for (int k2 = 0; k2 < 16; k2++) total += wsum[k2];
    int c = carry_s;
    int excl = c + woff + s - v;
    offs[i] = excl; cursor[i] = excl;
    __syncthreads();
    if (t == 0) carry_s = c + total;
    __syncthreads();
  }
  if (t == 0) { offs[NSUB] = carry_s; cursor[NSUB] = carry_s; }
}

__global__ void k_scatter(const int* __restrict__ edge_index, int* __restrict__ cursor,
                          int* __restrict__ csr) {
  int e = blockIdx.x * 256 + threadIdx.x;
  if (e < NEDGE) {
    int de = edge_index[NEDGE + e];
    int p = atomicAdd(&cursor[de], 1);
    csr[p] = e;
  }
}

// qkvs[N][512] = concat(memory,pos_memory)[n_id] @ [Wq|Wk|Wv|Wskip] + bias
__global__ __launch_bounds__(256)
void k_gemm_node(const float* __restrict__ mem, const float* __restrict__ pmem,
                 const int* __restrict__ n_id, const float* __restrict__ Wcat,
                 const float* __restrict__ bcat, float* __restrict__ qkvs) {
  __shared__ __align__(16) float sA[BK][LDT];
  __shared__ __align__(16) float sB[BK][LDT];
  int t = threadIdx.x;
  int row0 = blockIdx.x * 64;
  int col0 = blockIdx.y * 64;
  int ra = t >> 2, kqa = (t & 3) * 8;     // A: 4 threads/row, 8 k each
  int kb = t >> 3, cb8 = (t & 7) * 8;     // B: 8 threads/row, 8 cols each
  int ty4 = (t >> 4) * 4, tx4 = (t & 15) * 4;
  int nid = n_id[row0 + ra];
  const float* zlo = mem + (size_t)nid * 128;
  const float* zhi = pmem + (size_t)nid * 128;
  float acc[4][4] = {};
  for (int kc = 0; kc < 256; kc += BK) {
    int kg0 = kc + kqa;
    const float* zr = (kg0 < 128) ? (zlo + kg0) : (zhi + kg0 - 128);
    float4 a0 = *(const float4*)zr;
    float4 a1 = *(const float4*)(zr + 4);
    const float* br = Wcat + (size_t)(kc + kb) * 512 + col0 + cb8;
    float4 b0 = *(const float4*)br;
    float4 b1 = *(const float4*)(br + 4);
    __syncthreads();
    sA[kqa + 0][ra] = a0.x; sA[kqa + 1][ra] = a0.y; sA[kqa + 2][ra] = a0.z; sA[kqa + 3][ra] = a0.w;
    sA[kqa + 4][ra] = a1.x; sA[kqa + 5][ra] = a1.y; sA[kqa + 6][ra] = a1.z; sA[kqa + 7][ra] = a1.w;
    *(float4*)&sB[kb][cb8] = b0;
    *(float4*)&sB[kb][cb8 + 4] = b1;
    __syncthreads();
    #pragma unroll
    for (int kk = 0; kk < BK; kk++) {
      float4 a4 = *(const float4*)&sA[kk][ty4];
      float4 b4 = *(const float4*)&sB[kk][tx4];
      acc[0][0] += a4.x * b4.x; acc[0][1] += a4.x * b4.y; acc[0][2] += a4.x * b4.z; acc[0][3] += a4.x * b4.w;
      acc[1][0] += a4.y * b4.x; acc[1][1] += a4.y * b4.y; acc[1][2] += a4.y * b4.z; acc[1][3] += a4.y * b4.w;
      acc[2][0] += a4.z * b4.x; acc[2][1] += a4.z * b4.y; acc[2][2] += a4.z * b4.z; acc[2][3] += a4.z * b4.w;
      acc[3][0] += a4.w * b4.x; acc[3][1] += a4.w * b4.y; acc[3][2] += a4.w * b4.z; acc[3][3] += a4.w * b4.w;
    }
  }
  float4 bias = *(const float4*)&bcat[col0 + tx4];
  #pragma unroll
  for (int i = 0; i < 4; i++) {
    float4 cv;
    cv.x = acc[i][0] + bias.x; cv.y = acc[i][1] + bias.y;
    cv.z = acc[i][2] + bias.z; cv.w = acc[i][3] + bias.w;
    *(float4*)&qkvs[(size_t)(row0 + ty4 + i) * 512 + col0 + tx4] = cv;
  }
}

// per edge-tile: e = [cos(rel_t*tw+tb)|msg] @ We + be; fused epilogue computes
// score[e][head=blockIdx.y] and ve = v[se]+e (bf16). BN==HD so each col-block
// owns one head's complete score.
__global__ __launch_bounds__(256)
void k_gemm_edge(const float* __restrict__ rel_t, const float* __restrict__ time_w,
                 const float* __restrict__ time_b, const float* __restrict__ edge_msg,
                 const float* __restrict__ We, const float* __restrict__ be,
                 const int* __restrict__ edge_index, const float* __restrict__ qkvs,
                 float* __restrict__ score, unsigned short* __restrict__ vebuf) {
  __shared__ __align__(16) float sA[BK][LDT];
  __shared__ __align__(16) float sB[BK][LDT];
  int t = threadIdx.x;
  int row0 = blockIdx.x * 64;
  int col0 = blockIdx.y * 64;
  int ra = t >> 2, kqa = (t & 3) * 8;
  int kb = t >> 3, cb8 = (t & 7) * 8;
  int ty4 = (t >> 4) * 4, tx4 = (t & 15) * 4;
  float rt = rel_t[row0 + ra];
  float acc[4][4] = {};
  for (int kc = 0; kc < 128; kc += BK) {
    int kg0 = kc + kqa;
    float av[8];
    if (kg0 < 64) {
      #pragma unroll
      for (int i2 = 0; i2 < 8; i2++) {
        int k = kg0 + i2;
        av[i2] = cosf(rt * time_w[k] + time_b[k]);
      }
    } else {
      const float4* mp = (const float4*)(edge_msg + (size_t)(row0 + ra) * 64 + (kg0 - 64));
      float4 m0 = mp[0], m1 = mp[1];
      av[0] = m0.x; av[1] = m0.y; av[2] = m0.z; av[3] = m0.w;
      av[4] = m1.x; av[5] = m1.y; av[6] = m1.z; av[7] = m1.w;
    }
    const float* br = We + (size_t)(kc + kb) * 128 + col0 + cb8;
    float4 b0 = *(const float4*)br;
    float4 b1 = *(const float4*)(br + 4);
    __syncthreads();
    #pragma unroll
    for (int i2 = 0; i2 < 8; i2++) sA[kqa + i2][ra] = av[i2];
    *(float4*)&sB[kb][cb8] = b0;
    *(float4*)&sB[kb][cb8 + 4] = b1;
    __syncthreads();
    #pragma unroll
    for (int kk = 0; kk < BK; kk++) {
      float4 a4 = *(const float4*)&sA[kk][ty4];
      float4 b4 = *(const float4*)&sB[kk][tx4];
      acc[0][0] += a4.x * b4.x; acc[0][1] += a4.x * b4.y; acc[0][2] += a4.x * b4.z; acc[0][3] += a4.x * b4.w;
      acc[1][0] += a4.y * b4.x; acc[1][1] += a4.y * b4.y; acc[1][2] += a4.y * b4.z; acc[1][3] += a4.y * b4.w;
      acc[2][0] += a4.z * b4.x; acc[2][1] += a4.z * b4.y; acc[2][2] += a4.z * b4.z; acc[2][3] += a4.z * b4.w;
      acc[3][0] += a4.w * b4.x; acc[3][1] += a4.w * b4.y; acc[3][2] += a4.w * b4.z; acc[3][3] += a4.w * b4.w;
    }
  }
  int cb = blockIdx.y;
  int c0 = col0 + tx4;
  float4 biase = *(const float4*)&be[c0];
  #pragma unroll
  for (int i = 0; i < 4; i++) {
    int eid = row0 + ty4 + i;
    int se = edge_index[eid];
    int de = edge_index[NEDGE + eid];
    const float* kvp = qkvs + (size_t)se * 512;
    const float* qp  = qkvs + (size_t)de * 512;
    float e0 = acc[i][0] + biase.x;
    float e1 = acc[i][1] + biase.y;
    float e2 = acc[i][2] + biase.z;
    float e3 = acc[i][3] + biase.w;
    float sp = qp[c0 + 0] * (kvp[128 + c0 + 0] + e0)
             + qp[c0 + 1] * (kvp[128 + c0 + 1] + e1)
             + qp[c0 + 2] * (kvp[128 + c0 + 2] + e2)
             + qp[c0 + 3] * (kvp[128 + c0 + 3] + e3);
    ushort4 pk;
    pk.x = f2bf(kvp[256 + c0 + 0] + e0);
    pk.y = f2bf(kvp[256 + c0 + 1] + e1);
    pk.z = f2bf(kvp[256 + c0 + 2] + e2);
    pk.w = f2bf(kvp[256 + c0 + 3] + e3);
    *(ushort4*)(vebuf + (size_t)eid * 128 + c0) = pk;
    sp += __shfl_xor(sp, 1, 64);
    sp += __shfl_xor(sp, 2, 64);
    sp += __shfl_xor(sp, 4, 64);
    sp += __shfl_xor(sp, 8, 64);
    if ((t & 15) == 0) score[(size_t)eid * 2 + cb] = sp * 0.125f;   // /sqrt(64)
  }
}

// one wave per node: segment softmax (max,sum in-wave, no atomics) + aggregate
// + skip + fused 128->64 MLP
__global__ __launch_bounds__(256)
void k_agg_mlp(const float* __restrict__ qkvs, const float* __restrict__ score,
               const unsigned short* __restrict__ vebuf, const int* __restrict__ offs,
               const int* __restrict__ csr, const float* __restrict__ mlp_w,
               const float* __restrict__ mlp_b, float* __restrict__ h) {
  __shared__ float sOut[4][128];
  int t = threadIdx.x, w = t >> 6, l = t & 63;
  int node = blockIdx.x * 4 + w;
  int s0 = offs[node], s1 = offs[node + 1];
  float m0 = -INFINITY, m1 = -INFINITY;
  for (int idx = s0; idx < s1; idx++) {
    int eid = csr[idx];
    m0 = fmaxf(m0, score[(size_t)eid * 2]);
    m1 = fmaxf(m1, score[(size_t)eid * 2 + 1]);
  }
  float d0 = 0.f, d1 = 0.f, a0 = 0.f, a1 = 0.f;
  for (int idx = s0; idx < s1; idx++) {
    int eid = csr[idx];
    float ex0 = __expf(score[(size_t)eid * 2] - m0);
    float ex1 = __expf(score[(size_t)eid * 2 + 1] - m1);
    d0 += ex0; d1 += ex1;
    a0 += ex0 * bf2f(vebuf[(size_t)eid * 128 + l]);
    a1 += ex1 * bf2f(vebuf[(size_t)eid * 128 + 64 + l]);
  }
  float o0 = a0 / (d0 + 1e-16f) + qkvs[(size_t)node * 512 + 384 + l];
  float o1 = a1 / (d1 + 1e-16f) + qkvs[(size_t)node * 512 + 448 + l];
  sOut[w][l] = o0; sOut[w][64 + l] = o1;
  __syncthreads();
  float hv = mlp_b[l];
  #pragma unroll 8
  for (int c = 0; c < 128; c++) hv += sOut[w][c] * mlp_w[c * 64 + l];
  h[(size_t)node * 64 + l] = hv;
}

__global__ __launch_bounds__(256)
void k_linkpred(const float* __restrict__ h, const int* __restrict__ assoc,
                const int* __restrict__ src, const int* __restrict__ dst,
                const int* __restrict__ neg, const float* __restrict__ lps_w,
                const float* __restrict__ lps_b, const float* __restrict__ lpd_w,
                const float* __restrict__ lpd_b, const float* __restrict__ lpf_w,
                const float* __restrict__ lpf_b, float* __restrict__ out) {
  int t = threadIdx.x, w = t >> 6, j = t & 63;
  int b = blockIdx.x * 4 + w;
  const float* hs = h + (size_t)assoc[src[b]] * 64;
  const float* hd = h + (size_t)assoc[dst[b]] * 64;
  const float* hn = h + (size_t)assoc[neg[b]] * 64;
  float vs = lps_b[j], vd = lpd_b[j], vn = lpd_b[j];
  for (int k = 0; k < 64; k++) {
    float ws_ = lps_w[k * 64 + j];
    float wd_ = lpd_w[k * 64 + j];
    vs += hs[k] * ws_;
    vd += hd[k] * wd_;
    vn += hn[k] * wd_;
  }
  float fw = lpf_w[j];
  float hp = fmaxf(vs + vd, 0.f) * fw;
  float hq = fmaxf(vs + vn, 0.f) * fw;
  #pragma unroll
  for (int m = 1; m < 64; m <<= 1) {
    hp += __shfl_xor(hp, m, 64);
    hq += __shfl_xor(hq, m, 64);
  }
  if (j == 0) {
    out[b] = hp + lpf_b[0];
    out[NBATCH + b] = hq + lpf_b[0];
  }
}

extern "C" void kernel_launch(void* const* d_in, const int* in_sizes, int n_in,
                              void* d_out, int out_size, void* d_ws, size_t ws_size,
                              hipStream_t stream) {
  if (n_in < 30) return;
  const float* memory      = (const float*)d_in[0];
  const float* pos_memory  = (const float*)d_in[1];
  const float* last_update = (const float*)d_in[2];
  const int*   n_id        = (const int*)d_in[3];
  const int*   edge_index  = (const int*)d_in[4];
  const float* edge_t      = (const float*)d_in[5];
  const float* edge_msg    = (const float*)d_in[6];
  const int*   src         = (const int*)d_in[7];
  const int*   dst         = (const int*)d_in[8];
  const int*   neg_dst     = (const int*)d_in[9];
  const float* time_w      = (const float*)d_in[10];
  const float* time_b      = (const float*)d_in[11];
  const float* Wq = (const float*)d_in[12]; const float* bq = (const float*)d_in[13];
  const float* Wk = (const float*)d_in[14]; const float* bk = (const float*)d_in[15];
  const float* Wv = (const float*)d_in[16]; const float* bv = (const float*)d_in[17];
  const float* We = (const float*)d_in[18]; const float* be = (const float*)d_in[19];
  const float* Wskip = (const float*)d_in[20]; const float* bskip = (const float*)d_in[21];
  const float* mlp_w = (const float*)d_in[22]; const float* mlp_b = (const float*)d_in[23];
  const float* lps_w = (const float*)d_in[24]; const float* lps_b = (const float*)d_in[25];
  const float* lpd_w = (const float*)d_in[26]; const float* lpd_b = (const float*)d_in[27];
  const float* lpf_w = (const float*)d_in[28]; const float* lpf_b = (const float*)d_in[29];
  float* out = (float*)d_out;

  char* ws = (char*)d_ws;
  size_t off = 0;
  auto alloc = [&](size_t bytes) -> void* {
    void* p = ws + off;
    off += (bytes + 255) & ~(size_t)255;
    return p;
  };
  int*   assoc  = (int*)alloc((size_t)NNODES * 4);
  float* Wcat   = (float*)alloc((size_t)256 * 512 * 4);
  float* bcat   = (float*)alloc(512 * 4);
  float* rel_t  = (float*)alloc((size_t)NEDGE * 4);
  float* qkvs   = (float*)alloc((size_t)NSUB * 512 * 4);
  float* score  = (float*)alloc((size_t)NEDGE * 2 * 4);
  unsigned short* vebuf = (unsigned short*)alloc((size_t)NEDGE * 128 * 2);
  int*   deg    = (int*)alloc((size_t)NSUB * 4);
  int*   offs   = (int*)alloc((size_t)(NSUB + 1) * 4);
  int*   cursor = (int*)alloc((size_t)(NSUB + 1) * 4);
  int*   csr    = (int*)alloc((size_t)NEDGE * 4);
  float* hbuf   = (float*)alloc((size_t)NSUB * 64 * 4);

  if (ws_size < off) {
    k_sentinel<<<1, 1, 0, stream>>>(out);   // diagnosable failure: out[0]=-12345
    return;
  }

  (void)hipMemsetAsync(deg, 0, (size_t)NSUB * 4, stream);
  k_pack<<<(256 * 512 + 512 + 255) / 256, 256, 0, stream>>>(Wq, bq, Wk, bk, Wv, bv,
                                                            Wskip, bskip, Wcat, bcat);
  k_assoc<<<NSUB / 256, 256, 0, stream>>>(n_id, assoc);
  k_relt<<<NEDGE / 256, 256, 0, stream>>>(edge_index, n_id, last_update, edge_t, rel_t);
  k_gemm_node<<<dim3(NSUB / 64, 8), 256, 0, stream>>>(memory, pos_memory, n_id, Wcat, bcat, qkvs);
  k_gemm_edge<<<dim3(NEDGE / 64, 2), 256, 0, stream>>>(rel_t, time_w, time_b, edge_msg, We, be,
                                                       edge_index, qkvs, score, vebuf);
  k_deg<<<NEDGE / 256, 256, 0, stream>>>(edge_index, deg);
  k_scan<<<1, 1024, 0, stream>>>(deg, offs, cursor);
  k_scatter<<<NEDGE / 256, 256, 0, stream>>>(edge_index, cursor, csr);
  k_agg_mlp<<<NSUB / 4, 256, 0, stream>>>(qkvs, score, vebuf, offs, csr, mlp_w, mlp_b, hbuf);
  k_linkpred<<<NBATCH / 4, 256, 0, stream>>>(hbuf, assoc, src, dst, neg_dst,
                                             lps_w, lps_b, lpd_w, lpd_b, lpf_w, lpf_b, out);
}

// Round 2
// 785.134 us; speedup vs baseline: 1.6982x; 1.6982x over previous
//
#include <hip/hip_runtime.h>
#include <math.h>

#define NNODES 100000
#define NSUB   65536
#define NEDGE  655360
#define NBATCH 4096
#define LDK 72   // LDS k-stride (elements): 144B = 16B-multiple, 2-way conflicts only

typedef __attribute__((ext_vector_type(8))) short short8;
typedef __attribute__((ext_vector_type(4))) float f32x4;

__device__ __forceinline__ unsigned short f2bf(float x) {
  unsigned int b = __float_as_uint(x);
  b += 0x7fffu + ((b >> 16) & 1u);           // RNE
  return (unsigned short)(b >> 16);
}
__device__ __forceinline__ float bf2f(unsigned short u) {
  return __uint_as_float(((unsigned int)u) << 16);
}
__device__ __forceinline__ unsigned int pk2(float a, float b) {
  return (unsigned int)f2bf(a) | ((unsigned int)f2bf(b) << 16);
}

__global__ void k_sentinel(float* out) { out[0] = -12345.0f; }

// ---- weight packing -------------------------------------------------------
// Wt[768][256] bf16 (n-major, k contiguous). Output-column layout == nodeout:
// [0:128) q | [128:256) k interleaved (2l+h -> k_h[l]) | [256:384) v interleaved
// [384:512) skip | [512:768) qWe (h*128+kk), qWe = Wq_h @ We_h^T fused.
__global__ void k_packW(const float* __restrict__ Wq, const float* __restrict__ bq,
                        const float* __restrict__ Wk, const float* __restrict__ bk,
                        const float* __restrict__ Wv, const float* __restrict__ bv,
                        const float* __restrict__ Ws, const float* __restrict__ bs,
                        const float* __restrict__ We,
                        unsigned short* __restrict__ Wt, float* __restrict__ bias) {
  int n = blockIdx.x, r = threadIdx.x;   // n<768, r<256
  float v = 0.f, bn = 0.f;
  if (n < 128) { v = Wq[r * 128 + n]; bn = bq[n]; }
  else if (n < 256) { int i = n - 128, l = i >> 1, h = i & 1; v = Wk[r * 128 + h * 64 + l]; bn = bk[h * 64 + l]; }
  else if (n < 384) { int i = n - 256, l = i >> 1, h = i & 1; v = Wv[r * 128 + h * 64 + l]; bn = bv[h * 64 + l]; }
  else if (n < 512) { int c = n - 384; v = Ws[r * 128 + c]; bn = bs[c]; }
  else {
    int i = n - 512, h = i >> 7, kk = i & 127;
    float s = 0.f;
    for (int c = 0; c < 64; c++) s += Wq[r * 128 + h * 64 + c] * We[kk * 128 + h * 64 + c];
    v = s;
    if (r == 0) { float sb = 0.f; for (int c = 0; c < 64; c++) sb += bq[h * 64 + c] * We[kk * 128 + h * 64 + c]; bn = sb; }
  }
  Wt[(size_t)n * 256 + r] = f2bf(v);
  if (r == 0) bias[n] = bn;
}

// W2t[64][512] bf16: rows of A2 = [aggV'(128) | cos0 msg0 cos1 msg1 (256) | skip(128)]
// W2 = the corresponding slices of (mlp_w) and (We-part @ mlp_w).
__global__ void k_packW2(const float* __restrict__ We, const float* __restrict__ mlp_w,
                         unsigned short* __restrict__ W2t) {
  int r = blockIdx.x, j = threadIdx.x;   // r<512, j<64
  float v;
  if (r < 128) v = mlp_w[r * 64 + j];
  else if (r < 192) { int k = r - 128; float s = 0; for (int c = 0; c < 64; c++) s += We[k * 128 + c] * mlp_w[c * 64 + j]; v = s; }
  else if (r < 256) { int k = r - 192; float s = 0; for (int c = 0; c < 64; c++) s += We[(64 + k) * 128 + c] * mlp_w[c * 64 + j]; v = s; }
  else if (r < 320) { int k = r - 256; float s = 0; for (int c = 0; c < 64; c++) s += We[k * 128 + 64 + c] * mlp_w[(64 + c) * 64 + j]; v = s; }
  else if (r < 384) { int k = r - 320; float s = 0; for (int c = 0; c < 64; c++) s += We[(64 + k) * 128 + 64 + c] * mlp_w[(64 + c) * 64 + j]; v = s; }
  else v = mlp_w[(r - 384) * 64 + j];
  W2t[(size_t)j * 512 + r] = f2bf(v);
}

__global__ void k_bem(const float* __restrict__ be, const float* __restrict__ mlp_w,
                      float* __restrict__ bem) {
  int h = blockIdx.x, j = threadIdx.x;
  float s = 0.f;
  for (int c = 0; c < 64; c++) s += be[h * 64 + c] * mlp_w[(h * 64 + c) * 64 + j];
  bem[h * 64 + j] = s;
}

// ---- graph prep -----------------------------------------------------------
__global__ void k_assoc(const int* __restrict__ n_id, int* __restrict__ assoc) {
  int i = blockIdx.x * 256 + threadIdx.x;
  if (i < NSUB) assoc[n_id[i]] = i;
}

__global__ void k_relt(const int* __restrict__ edge_index, const int* __restrict__ n_id,
                       const float* __restrict__ last_update, const float* __restrict__ edge_t,
                       float* __restrict__ rel_t) {
  int e = blockIdx.x * 256 + threadIdx.x;
  if (e < NEDGE) rel_t[e] = last_update[n_id[edge_index[e]]] - edge_t[e];
}

__global__ void k_deg(const int* __restrict__ edge_index, int* __restrict__ deg) {
  int e = blockIdx.x * 256 + threadIdx.x;
  if (e < NEDGE) atomicAdd(&deg[edge_index[NEDGE + e]], 1);
}

__global__ __launch_bounds__(1024)
void k_scan(const int* __restrict__ deg, int* __restrict__ offs, int* __restrict__ cursor) {
  __shared__ int wsum[16];
  __shared__ int carry_s;
  int t = threadIdx.x, w = t >> 6, l = t & 63;
  if (t == 0) carry_s = 0;
  __syncthreads();
  for (int base = 0; base < NSUB; base += 1024) {
    int i = base + t;
    int v = deg[i];
    int s = v;
    #pragma unroll
    for (int d = 1; d < 64; d <<= 1) {
      int u = __shfl_up(s, d, 64);
      if (l >= d) s += u;
    }
    if (l == 63) wsum[w] = s;
    __syncthreads();
    int woff = 0;
    for (int k2 = 0; k2 < w; k2++) woff += wsum[k2];
    int total = 0;
    for (int k2 = 0; k2 < 16; k2++) total += wsum[k2];
    int c = carry_s;
    int excl = c + woff + s - v;
    offs[i] = excl; cursor[i] = excl;
    __syncthreads();
    if (t == 0) carry_s = c + total;
    __syncthreads();
  }
  if (t == 0) { offs[NSUB] = carry_s; cursor[NSUB] = carry_s; }
}

__global__ void k_scatter(const int* __restrict__ edge_index, int* __restrict__ cursor,
                          int* __restrict__ csr) {
  int e = blockIdx.x * 256 + threadIdx.x;
  if (e < NEDGE) {
    int p = atomicAdd(&cursor[edge_index[NEDGE + e]], 1);
    csr[p] = e;
  }
}

// ---- node GEMM: [65536,256] @ [256,768] bf16 MFMA -> nodeout bf16 ---------
__global__ __launch_bounds__(256)
void k_gemm_node(const float* __restrict__ mem, const float* __restrict__ pmem,
                 const int* __restrict__ n_id, const unsigned short* __restrict__ Wt,
                 const float* __restrict__ bias, unsigned short* __restrict__ nodeout) {
  __shared__ unsigned short sA[128][LDK];
  __shared__ unsigned short sB[128][LDK];
  int t = threadIdx.x;
  int row0 = blockIdx.x * 128, n0 = blockIdx.y * 128;
  int ar = t >> 1, ak = (t & 1) * 32;           // A: 2 thr/row, 32 k each
  int nid = n_id[row0 + ar];
  const float* arow0 = mem + (size_t)nid * 128;
  const float* arow1 = pmem + (size_t)nid * 128;
  int br = t >> 1;                               // B: 2 thr/row, 4x uint4 each
  int w = t >> 6, lane = t & 63, quad = lane >> 4, r16 = lane & 15;
  int m_off = (w >> 1) * 64, n_off = (w & 1) * 64;
  f32x4 acc[4][4] = {};
  for (int st = 0; st < 4; st++) {
    int ks = st * 64;
    const float* src = (ks < 128) ? (arow0 + ks + ak) : (arow1 + (ks - 128) + ak);
    __syncthreads();
    #pragma unroll
    for (int i = 0; i < 8; i++) {
      float4 f = *(const float4*)(src + i * 4);
      *(uint2*)&sA[ar][ak + i * 4] = make_uint2(pk2(f.x, f.y), pk2(f.z, f.w));
    }
    #pragma unroll
    for (int j = 0; j < 4; j++) {
      int c = (t & 1) * 4 + j;
      *(uint4*)&sB[br][c * 8] = *(const uint4*)(Wt + (size_t)(n0 + br) * 256 + ks + c * 8);
    }
    __syncthreads();
    #pragma unroll
    for (int kk = 0; kk < 2; kk++) {
      short8 af[4], bf_[4];
      #pragma unroll
      for (int i = 0; i < 4; i++) af[i]  = *(const short8*)&sA[m_off + i * 16 + r16][kk * 32 + quad * 8];
      #pragma unroll
      for (int i = 0; i < 4; i++) bf_[i] = *(const short8*)&sB[n_off + i * 16 + r16][kk * 32 + quad * 8];
      #pragma unroll
      for (int i = 0; i < 4; i++)
        #pragma unroll
        for (int j = 0; j < 4; j++)
          acc[i][j] = __builtin_amdgcn_mfma_f32_16x16x32_bf16(af[i], bf_[j], acc[i][j], 0, 0, 0);
    }
  }
  #pragma unroll
  for (int j = 0; j < 4; j++) {
    int col = n0 + n_off + j * 16 + r16;
    float bv_ = bias[col];
    #pragma unroll
    for (int i = 0; i < 4; i++) {
      int rbase = row0 + m_off + i * 16 + quad * 4;
      #pragma unroll
      for (int rg = 0; rg < 4; rg++)
        nodeout[(size_t)(rbase + rg) * 768 + col] = f2bf(acc[i][j][rg] + bv_);
    }
  }
}

// ---- fused edge pass: one wave per dest node, online softmax --------------
// score_h = (q_h.k_h + qWe_h[0:64].cos + qWe_h[64:128].msg + q_h.be_h)/8
// accumulates aggV (v moment), aggC/aggM (attr moments), denom per head.
__global__ __launch_bounds__(256)
void k_edge(const unsigned short* __restrict__ nodeout, const int* __restrict__ edge_index,
            const float* __restrict__ rel_t, const float* __restrict__ edge_msg,
            const float* __restrict__ time_w, const float* __restrict__ time_b,
            const float* __restrict__ be, const int* __restrict__ offs,
            const int* __restrict__ csr, unsigned short* __restrict__ aggbuf,
            float* __restrict__ salph) {
  int t = threadIdx.x, w = t >> 6, l = t & 63;
  int node = blockIdx.x * 4 + w;
  const unsigned short* nr = nodeout + (size_t)node * 768;
  float q0 = bf2f(nr[l]),       q1 = bf2f(nr[64 + l]);
  float qc0 = bf2f(nr[512 + l]), qm0 = bf2f(nr[576 + l]);
  float qc1 = bf2f(nr[640 + l]), qm1 = bf2f(nr[704 + l]);
  float tw = time_w[l], tb = time_b[l];
  float qbe0 = q0 * be[l], qbe1 = q1 * be[64 + l];
  #pragma unroll
  for (int s = 1; s < 64; s <<= 1) { qbe0 += __shfl_xor(qbe0, s, 64); qbe1 += __shfl_xor(qbe1, s, 64); }
  float m0 = -INFINITY, m1 = -INFINITY, d0 = 0.f, d1 = 0.f;
  float aV0 = 0, aV1 = 0, aC0 = 0, aM0 = 0, aC1 = 0, aM1 = 0;
  int e0 = offs[node], e1 = offs[node + 1];
  for (int idx = e0; idx < e1; idx++) {
    int eid = csr[idx];
    int se = edge_index[eid];
    float rt = rel_t[eid];
    const unsigned short* ns = nodeout + (size_t)se * 768;
    unsigned int kv = *(const unsigned int*)(ns + 128 + 2 * l);
    unsigned int vv = *(const unsigned int*)(ns + 256 + 2 * l);
    float mg = edge_msg[(size_t)eid * 64 + l];
    float cv = __cosf(rt * tw + tb);
    float k0 = bf2f((unsigned short)kv), k1 = bf2f((unsigned short)(kv >> 16));
    float v0 = bf2f((unsigned short)vv), v1 = bf2f((unsigned short)(vv >> 16));
    float p0 = q0 * k0 + qc0 * cv + qm0 * mg;
    float p1 = q1 * k1 + qc1 * cv + qm1 * mg;
    #pragma unroll
    for (int s = 1; s < 64; s <<= 1) { p0 += __shfl_xor(p0, s, 64); p1 += __shfl_xor(p1, s, 64); }
    float s0 = (p0 + qbe0) * 0.125f, s1 = (p1 + qbe1) * 0.125f;
    float nm0 = fmaxf(m0, s0), nm1 = fmaxf(m1, s1);
    float sc0 = __expf(m0 - nm0), sc1 = __expf(m1 - nm1);
    float w0 = __expf(s0 - nm0), w1 = __expf(s1 - nm1);
    d0 = d0 * sc0 + w0; d1 = d1 * sc1 + w1;
    aV0 = aV0 * sc0 + w0 * v0; aC0 = aC0 * sc0 + w0 * cv; aM0 = aM0 * sc0 + w0 * mg;
    aV1 = aV1 * sc1 + w1 * v1; aC1 = aC1 * sc1 + w1 * cv; aM1 = aM1 * sc1 + w1 * mg;
    m0 = nm0; m1 = nm1;
  }
  float i0 = 1.f / (d0 + 1e-16f), i1 = 1.f / (d1 + 1e-16f);
  unsigned short* ag = aggbuf + (size_t)node * 512;
  ag[l]       = f2bf(aV0 * i0); ag[64 + l]  = f2bf(aV1 * i1);
  ag[128 + l] = f2bf(aC0 * i0); ag[192 + l] = f2bf(aM0 * i0);
  ag[256 + l] = f2bf(aC1 * i1); ag[320 + l] = f2bf(aM1 * i1);
  ag[384 + l] = nr[384 + l];    ag[448 + l] = nr[448 + l];   // skip passthrough
  if (l == 0) { salph[node * 2] = d0 * i0; salph[node * 2 + 1] = d1 * i1; }
}

// ---- final GEMM: [65536,512] @ [512,64] bf16 MFMA -> h fp32 ---------------
__global__ __launch_bounds__(128)
void k_gemm_final(const unsigned short* __restrict__ aggbuf, const unsigned short* __restrict__ W2t,
                  const float* __restrict__ salph, const float* __restrict__ bem,
                  const float* __restrict__ mlp_b, float* __restrict__ h) {
  __shared__ unsigned short sA[128][LDK];
  __shared__ unsigned short sB[64][LDK];
  int t = threadIdx.x;
  int row0 = blockIdx.x * 128;
  int w = t >> 6, lane = t & 63, quad = lane >> 4, r16 = lane & 15;
  int m_off = w * 64;
  f32x4 acc[4][4] = {};
  for (int st = 0; st < 8; st++) {
    int ks = st * 64;
    __syncthreads();
    #pragma unroll
    for (int c = 0; c < 8; c++)
      *(uint4*)&sA[t][c * 8] = *(const uint4*)(aggbuf + (size_t)(row0 + t) * 512 + ks + c * 8);
    int brr = t >> 1;
    #pragma unroll
    for (int j = 0; j < 4; j++) {
      int c = (t & 1) * 4 + j;
      *(uint4*)&sB[brr][c * 8] = *(const uint4*)(W2t + (size_t)brr * 512 + ks + c * 8);
    }
    __syncthreads();
    #pragma unroll
    for (int kk = 0; kk < 2; kk++) {
      short8 af[4], bf_[4];
      #pragma unroll
      for (int i = 0; i < 4; i++) af[i]  = *(const short8*)&sA[m_off + i * 16 + r16][kk * 32 + quad * 8];
      #pragma unroll
      for (int i = 0; i < 4; i++) bf_[i] = *(const short8*)&sB[i * 16 + r16][kk * 32 + quad * 8];
      #pragma unroll
      for (int i = 0; i < 4; i++)
        #pragma unroll
        for (int j = 0; j < 4; j++)
          acc[i][j] = __builtin_amdgcn_mfma_f32_16x16x32_bf16(af[i], bf_[j], acc[i][j], 0, 0, 0);
    }
  }
  #pragma unroll
  for (int j = 0; j < 4; j++) {
    int col = j * 16 + r16;
    float mb = mlp_b[col], b0 = bem[col], b1 = bem[64 + col];
    #pragma unroll
    for (int i = 0; i < 4; i++) {
      int rbase = row0 + m_off + i * 16 + quad * 4;
      #pragma unroll
      for (int rg = 0; rg < 4; rg++) {
        int rr = rbase + rg;
        h[(size_t)rr * 64 + col] = acc[i][j][rg] + mb + salph[rr * 2] * b0 + salph[rr * 2 + 1] * b1;
      }
    }
  }
}

__global__ __launch_bounds__(256)
void k_linkpred(const float* __restrict__ h, const int* __restrict__ assoc,
                const int* __restrict__ src, const int* __restrict__ dst,
                const int* __restrict__ neg, const float* __restrict__ lps_w,
                const float* __restrict__ lps_b, const float* __restrict__ lpd_w,
                const float* __restrict__ lpd_b, const float* __restrict__ lpf_w,
                const float* __restrict__ lpf_b, float* __restrict__ out) {
  int t = threadIdx.x, w = t >> 6, j = t & 63;
  int b = blockIdx.x * 4 + w;
  const float* hs = h + (size_t)assoc[src[b]] * 64;
  const float* hd = h + (size_t)assoc[dst[b]] * 64;
  const float* hn = h + (size_t)assoc[neg[b]] * 64;
  float vs = lps_b[j], vd = lpd_b[j], vn = lpd_b[j];
  for (int k = 0; k < 64; k++) {
    float ws_ = lps_w[k * 64 + j];
    float wd_ = lpd_w[k * 64 + j];
    vs += hs[k] * ws_;
    vd += hd[k] * wd_;
    vn += hn[k] * wd_;
  }
  float fw = lpf_w[j];
  float hp = fmaxf(vs + vd, 0.f) * fw;
  float hq = fmaxf(vs + vn, 0.f) * fw;
  #pragma unroll
  for (int m = 1; m < 64; m <<= 1) {
    hp += __shfl_xor(hp, m, 64);
    hq += __shfl_xor(hq, m, 64);
  }
  if (j == 0) {
    out[b] = hp + lpf_b[0];
    out[NBATCH + b] = hq + lpf_b[0];
  }
}

extern "C" void kernel_launch(void* const* d_in, const int* in_sizes, int n_in,
                              void* d_out, int out_size, void* d_ws, size_t ws_size,
                              hipStream_t stream) {
  if (n_in < 30) return;
  const float* memory      = (const float*)d_in[0];
  const float* pos_memory  = (const float*)d_in[1];
  const float* last_update = (const float*)d_in[2];
  const int*   n_id        = (const int*)d_in[3];
  const int*   edge_index  = (const int*)d_in[4];
  const float* edge_t      = (const float*)d_in[5];
  const float* edge_msg    = (const float*)d_in[6];
  const int*   src         = (const int*)d_in[7];
  const int*   dst         = (const int*)d_in[8];
  const int*   neg_dst     = (const int*)d_in[9];
  const float* time_w      = (const float*)d_in[10];
  const float* time_b      = (const float*)d_in[11];
  const float* Wq = (const float*)d_in[12]; const float* bq = (const float*)d_in[13];
  const float* Wk = (const float*)d_in[14]; const float* bk = (const float*)d_in[15];
  const float* Wv = (const float*)d_in[16]; const float* bv = (const float*)d_in[17];
  const float* We = (const float*)d_in[18]; const float* be = (const float*)d_in[19];
  const float* Wskip = (const float*)d_in[20]; const float* bskip = (const float*)d_in[21];
  const float* mlp_w = (const float*)d_in[22]; const float* mlp_b = (const float*)d_in[23];
  const float* lps_w = (const float*)d_in[24]; const float* lps_b = (const float*)d_in[25];
  const float* lpd_w = (const float*)d_in[26]; const float* lpd_b = (const float*)d_in[27];
  const float* lpf_w = (const float*)d_in[28]; const float* lpf_b = (const float*)d_in[29];
  float* out = (float*)d_out;

  char* ws = (char*)d_ws;
  size_t off = 0;
  auto alloc = [&](size_t bytes) -> void* {
    void* p = ws + off;
    off += (bytes + 255) & ~(size_t)255;
    return p;
  };
  int*   assoc   = (int*)alloc((size_t)NNODES * 4);
  unsigned short* Wt  = (unsigned short*)alloc((size_t)768 * 256 * 2);
  float* bias    = (float*)alloc(768 * 4);
  unsigned short* W2t = (unsigned short*)alloc((size_t)64 * 512 * 2);
  float* bem     = (float*)alloc(128 * 4);
  float* rel_t   = (float*)alloc((size_t)NEDGE * 4);
  unsigned short* nodeout = (unsigned short*)alloc((size_t)NSUB * 768 * 2);
  unsigned short* aggbuf  = (unsigned short*)alloc((size_t)NSUB * 512 * 2);
  float* salph   = (float*)alloc((size_t)NSUB * 2 * 4);
  int*   deg     = (int*)alloc((size_t)NSUB * 4);
  int*   offs    = (int*)alloc((size_t)(NSUB + 1) * 4);
  int*   cursor  = (int*)alloc((size_t)(NSUB + 1) * 4);
  int*   csr     = (int*)alloc((size_t)NEDGE * 4);
  float* hbuf    = (float*)alloc((size_t)NSUB * 64 * 4);

  if (ws_size < off) {
    k_sentinel<<<1, 1, 0, stream>>>(out);
    return;
  }

  (void)hipMemsetAsync(deg, 0, (size_t)NSUB * 4, stream);
  k_packW<<<768, 256, 0, stream>>>(Wq, bq, Wk, bk, Wv, bv, Wskip, bskip, We, Wt, bias);
  k_packW2<<<512, 64, 0, stream>>>(We, mlp_w, W2t);
  k_bem<<<2, 64, 0, stream>>>(be, mlp_w, bem);
  k_assoc<<<NSUB / 256, 256, 0, stream>>>(n_id, assoc);
  k_relt<<<NEDGE / 256, 256, 0, stream>>>(edge_index, n_id, last_update, edge_t, rel_t);
  k_deg<<<NEDGE / 256, 256, 0, stream>>>(edge_index, deg);
  k_scan<<<1, 1024, 0, stream>>>(deg, offs, cursor);
  k_scatter<<<NEDGE / 256, 256, 0, stream>>>(edge_index, cursor, csr);
  k_gemm_node<<<dim3(NSUB / 128, 6), 256, 0, stream>>>(memory, pos_memory, n_id, Wt, bias, nodeout);
  k_edge<<<NSUB / 4, 256, 0, stream>>>(nodeout, edge_index, rel_t, edge_msg, time_w, time_b,
                                       be, offs, csr, aggbuf, salph);
  k_gemm_final<<<NSUB / 128, 128, 0, stream>>>(aggbuf, W2t, salph, bem, mlp_b, hbuf);
  k_linkpred<<<NBATCH / 4, 256, 0, stream>>>(hbuf, assoc, src, dst, neg_dst,
                                             lps_w, lps_b, lpd_w, lpd_b, lpf_w, lpf_b, out);
}

// Round 3
// 741.642 us; speedup vs baseline: 1.7978x; 1.0586x over previous
//
#include <hip/hip_runtime.h>
#include <math.h>

#define NNODES 100000
#define NSUB   65536
#define NEDGE  655360
#define NBATCH 4096
#define LDK 72   // LDS k-stride (elements): 144B, 16B-aligned rows, 2-way conflicts only

typedef __attribute__((ext_vector_type(8))) short short8;
typedef __attribute__((ext_vector_type(4))) float f32x4;

__device__ __forceinline__ unsigned short f2bf(float x) {
  unsigned int b = __float_as_uint(x);
  b += 0x7fffu + ((b >> 16) & 1u);           // RNE
  return (unsigned short)(b >> 16);
}
__device__ __forceinline__ float bf2f(unsigned short u) {
  return __uint_as_float(((unsigned int)u) << 16);
}
__device__ __forceinline__ float bflo(unsigned int u) { return __uint_as_float(u << 16); }
__device__ __forceinline__ float bfhi(unsigned int u) { return __uint_as_float(u & 0xffff0000u); }
__device__ __forceinline__ unsigned int pk2(float a, float b) {
  return (unsigned int)f2bf(a) | ((unsigned int)f2bf(b) << 16);
}
__device__ __forceinline__ void unpack8(uint4 u, float* a, float* b) {
  a[0] = bflo(u.x); b[0] = bfhi(u.x);
  a[1] = bflo(u.y); b[1] = bfhi(u.y);
  a[2] = bflo(u.z); b[2] = bfhi(u.z);
  a[3] = bflo(u.w); b[3] = bfhi(u.w);
}
__device__ __forceinline__ ushort4 pkv4(float a, float b, float c, float d) {
  return make_ushort4(f2bf(a), f2bf(b), f2bf(c), f2bf(d));
}

__global__ void k_sentinel(float* out) { out[0] = -12345.0f; }

// ---- weight packing -------------------------------------------------------
// Wt[768][256] bf16, n-major. Column layout (== nodeout row layout):
// [0:128)   q interleaved (2l+h), PRE-SCALED by 1/8
// [128:256) k interleaved (2l+h)
// [256:384) v interleaved (2l+h)
// [384:512) skip
// [512:640) qWe-cos interleaved (2c+h), pre-scaled 1/8   (qWe_h = Wq_h @ We_h^T)
// [640:768) qWe-msg interleaved (2c+h), pre-scaled 1/8
__global__ void k_packW(const float* __restrict__ Wq, const float* __restrict__ bq,
                        const float* __restrict__ Wk, const float* __restrict__ bk,
                        const float* __restrict__ Wv, const float* __restrict__ bv,
                        const float* __restrict__ Ws, const float* __restrict__ bs,
                        const float* __restrict__ We,
                        unsigned short* __restrict__ Wt, float* __restrict__ bias) {
  int n = blockIdx.x, r = threadIdx.x;   // n<768, r<256
  float v = 0.f, bn = 0.f;
  if (n < 128) {
    int l = n >> 1, h = n & 1;
    v = Wq[r * 128 + h * 64 + l] * 0.125f; bn = bq[h * 64 + l] * 0.125f;
  } else if (n < 256) {
    int i = n - 128, l = i >> 1, h = i & 1;
    v = Wk[r * 128 + h * 64 + l]; bn = bk[h * 64 + l];
  } else if (n < 384) {
    int i = n - 256, l = i >> 1, h = i & 1;
    v = Wv[r * 128 + h * 64 + l]; bn = bv[h * 64 + l];
  } else if (n < 512) {
    int c = n - 384; v = Ws[r * 128 + c]; bn = bs[c];
  } else {
    int i = (n < 640) ? (n - 512) : (n - 640);
    int c = i >> 1, h = i & 1;
    int kk = (n < 640) ? c : (64 + c);
    float s = 0.f;
    for (int d = 0; d < 64; d++) s += Wq[r * 128 + h * 64 + d] * We[kk * 128 + h * 64 + d];
    v = s * 0.125f;
    if (r == 0) {
      float sb = 0.f;
      for (int d = 0; d < 64; d++) sb += bq[h * 64 + d] * We[kk * 128 + h * 64 + d];
      bn = sb * 0.125f;
    }
  }
  Wt[(size_t)n * 256 + r] = f2bf(v);
  if (r == 0) bias[n] = bn;
}

// W2t[64][512] bf16: cols of A2 = [aggV(128) | cos0 msg0 cos1 msg1 (256) | skip(128)]
__global__ void k_packW2(const float* __restrict__ We, const float* __restrict__ mlp_w,
                         unsigned short* __restrict__ W2t) {
  int r = blockIdx.x, j = threadIdx.x;   // r<512, j<64
  float v;
  if (r < 128) v = mlp_w[r * 64 + j];
  else if (r < 192) { int k = r - 128; float s = 0; for (int c = 0; c < 64; c++) s += We[k * 128 + c] * mlp_w[c * 64 + j]; v = s; }
  else if (r < 256) { int k = r - 192; float s = 0; for (int c = 0; c < 64; c++) s += We[(64 + k) * 128 + c] * mlp_w[c * 64 + j]; v = s; }
  else if (r < 320) { int k = r - 256; float s = 0; for (int c = 0; c < 64; c++) s += We[k * 128 + 64 + c] * mlp_w[(64 + c) * 64 + j]; v = s; }
  else if (r < 384) { int k = r - 320; float s = 0; for (int c = 0; c < 64; c++) s += We[(64 + k) * 128 + 64 + c] * mlp_w[(64 + c) * 64 + j]; v = s; }
  else v = mlp_w[(r - 384) * 64 + j];
  W2t[(size_t)j * 512 + r] = f2bf(v);
}

__global__ void k_bem(const float* __restrict__ be, const float* __restrict__ mlp_w,
                      float* __restrict__ bem) {
  int h = blockIdx.x, j = threadIdx.x;
  float s = 0.f;
  for (int c = 0; c < 64; c++) s += be[h * 64 + c] * mlp_w[(h * 64 + c) * 64 + j];
  bem[h * 64 + j] = s;
}

// ---- prep ----------------------------------------------------------------
__global__ void k_assoc(const int* __restrict__ n_id, int* __restrict__ assoc) {
  int i = blockIdx.x * 256 + threadIdx.x;
  if (i < NSUB) assoc[n_id[i]] = i;
}

// anodes[NSUB][256] bf16 = concat(memory,pos_memory)[n_id], gathered+converted once
__global__ void k_packA(const float* __restrict__ mem, const float* __restrict__ pmem,
                        const int* __restrict__ n_id, unsigned short* __restrict__ anodes) {
  int i = blockIdx.x * 256 + threadIdx.x;   // 8-elem chunk index
  int node = i >> 5, ch = i & 31;
  int nid = n_id[node];
  const float* src = (ch < 16) ? (mem + (size_t)nid * 128 + ch * 8)
                               : (pmem + (size_t)nid * 128 + (ch - 16) * 8);
  float4 f0 = *(const float4*)src, f1 = *(const float4*)(src + 4);
  uint4 o;
  o.x = pk2(f0.x, f0.y); o.y = pk2(f0.z, f0.w);
  o.z = pk2(f1.x, f1.y); o.w = pk2(f1.z, f1.w);
  *(uint4*)(anodes + (size_t)node * 256 + ch * 8) = o;
}

__global__ void k_prep_edge(const int* __restrict__ edge_index, const int* __restrict__ n_id,
                            const float* __restrict__ last_update, const float* __restrict__ edge_t,
                            float* __restrict__ rel_t, int* __restrict__ deg) {
  int e = blockIdx.x * 256 + threadIdx.x;
  if (e < NEDGE) {
    rel_t[e] = last_update[n_id[edge_index[e]]] - edge_t[e];
    atomicAdd(&deg[edge_index[NEDGE + e]], 1);
  }
}

__global__ __launch_bounds__(1024)
void k_scan(const int* __restrict__ deg, int* __restrict__ offs, int* __restrict__ cursor) {
  __shared__ int wsum[16];
  __shared__ int carry_s;
  int t = threadIdx.x, w = t >> 6, l = t & 63;
  if (t == 0) carry_s = 0;
  __syncthreads();
  for (int base = 0; base < NSUB; base += 1024) {
    int i = base + t;
    int v = deg[i];
    int s = v;
    #pragma unroll
    for (int d = 1; d < 64; d <<= 1) {
      int u = __shfl_up(s, d, 64);
      if (l >= d) s += u;
    }
    if (l == 63) wsum[w] = s;
    __syncthreads();
    int woff = 0;
    for (int k2 = 0; k2 < w; k2++) woff += wsum[k2];
    int total = 0;
    for (int k2 = 0; k2 < 16; k2++) total += wsum[k2];
    int c = carry_s;
    int excl = c + woff + s - v;
    offs[i] = excl; cursor[i] = excl;
    __syncthreads();
    if (t == 0) carry_s = c + total;
    __syncthreads();
  }
  if (t == 0) { offs[NSUB] = carry_s; cursor[NSUB] = carry_s; }
}

__global__ void k_scatter(const int* __restrict__ edge_index, int* __restrict__ cursor,
                          int* __restrict__ csr) {
  int e = blockIdx.x * 256 + threadIdx.x;
  if (e < NEDGE) {
    int p = atomicAdd(&cursor[edge_index[NEDGE + e]], 1);
    csr[p] = e;
  }
}

// ---- node GEMM: [65536,256] @ [256,768] bf16 MFMA -> nodeout bf16 ---------
__global__ __launch_bounds__(256)
void k_gemm_node(const unsigned short* __restrict__ anodes, const unsigned short* __restrict__ Wt,
                 const float* __restrict__ bias, unsigned short* __restrict__ nodeout) {
  __shared__ unsigned short sA[128][LDK];
  __shared__ unsigned short sB[128][LDK];
  int t = threadIdx.x;
  int row0 = blockIdx.x * 128, n0 = blockIdx.y * 128;
  int ar = t >> 1, ak = (t & 1) * 32;           // 2 thr/row, 32 bf16 each
  int w = t >> 6, lane = t & 63, quad = lane >> 4, r16 = lane & 15;
  int m_off = (w >> 1) * 64, n_off = (w & 1) * 64;
  f32x4 acc[4][4] = {};
  for (int st = 0; st < 4; st++) {
    int ks = st * 64;
    __syncthreads();
    #pragma unroll
    for (int i = 0; i < 4; i++)
      *(uint4*)&sA[ar][ak + i * 8] = *(const uint4*)(anodes + (size_t)(row0 + ar) * 256 + ks + ak + i * 8);
    #pragma unroll
    for (int i = 0; i < 4; i++)
      *(uint4*)&sB[ar][ak + i * 8] = *(const uint4*)(Wt + (size_t)(n0 + ar) * 256 + ks + ak + i * 8);
    __syncthreads();
    #pragma unroll
    for (int kk = 0; kk < 2; kk++) {
      short8 af[4], bf_[4];
      #pragma unroll
      for (int i = 0; i < 4; i++) af[i]  = *(const short8*)&sA[m_off + i * 16 + r16][kk * 32 + quad * 8];
      #pragma unroll
      for (int i = 0; i < 4; i++) bf_[i] = *(const short8*)&sB[n_off + i * 16 + r16][kk * 32 + quad * 8];
      #pragma unroll
      for (int i = 0; i < 4; i++)
        #pragma unroll
        for (int j = 0; j < 4; j++)
          acc[i][j] = __builtin_amdgcn_mfma_f32_16x16x32_bf16(af[i], bf_[j], acc[i][j], 0, 0, 0);
    }
  }
  #pragma unroll
  for (int j = 0; j < 4; j++) {
    int col = n0 + n_off + j * 16 + r16;
    float bv_ = bias[col];
    #pragma unroll
    for (int i = 0; i < 4; i++) {
      int rbase = row0 + m_off + i * 16 + quad * 4;
      #pragma unroll
      for (int rg = 0; rg < 4; rg++)
        nodeout[(size_t)(rbase + rg) * 768 + col] = f2bf(acc[i][j][rg] + bv_);
    }
  }
}

// ---- fused edge pass: 16-lane group per dest node (4 nodes/wave) ----------
// score_h = q_h.k_h + qWe_h.attr + q_h.be_h  (all q terms pre-scaled by 1/8)
// no max-subtraction (scores O(1) for normalized data; softmax shift-invariant)
__global__ __launch_bounds__(256)
void k_edge(const unsigned short* __restrict__ nodeout, const int* __restrict__ edge_index,
            const float* __restrict__ rel_t, const float* __restrict__ edge_msg,
            const float* __restrict__ time_w, const float* __restrict__ time_b,
            const float* __restrict__ be, const int* __restrict__ offs,
            const int* __restrict__ csr, unsigned short* __restrict__ aggbuf,
            float* __restrict__ salph) {
  int t = threadIdx.x, w = t >> 6, lane = t & 63;
  int j = lane & 15;
  int node = blockIdx.x * 16 + w * 4 + (lane >> 4);
  const unsigned short* nr = nodeout + (size_t)node * 768;
  uint4 q4  = *(const uint4*)(nr + 8 * j);
  uint4 qc4 = *(const uint4*)(nr + 512 + 8 * j);
  uint4 qm4 = *(const uint4*)(nr + 640 + 8 * j);
  float4 tw4 = *(const float4*)(time_w + 4 * j);
  float4 tb4 = *(const float4*)(time_b + 4 * j);
  float4 beA = *(const float4*)(be + 4 * j);
  float4 beB = *(const float4*)(be + 64 + 4 * j);
  float q0[4], q1[4], qc0[4], qc1[4], qm0[4], qm1[4];
  unpack8(q4, q0, q1); unpack8(qc4, qc0, qc1); unpack8(qm4, qm0, qm1);
  float qbe0 = q0[0] * beA.x + q0[1] * beA.y + q0[2] * beA.z + q0[3] * beA.w;
  float qbe1 = q1[0] * beB.x + q1[1] * beB.y + q1[2] * beB.z + q1[3] * beB.w;
  #pragma unroll
  for (int s = 1; s < 16; s <<= 1) { qbe0 += __shfl_xor(qbe0, s, 64); qbe1 += __shfl_xor(qbe1, s, 64); }
  float d0 = 0.f, d1 = 0.f;
  float aV0[4] = {}, aV1[4] = {}, aC0[4] = {}, aC1[4] = {}, aM0[4] = {}, aM1[4] = {};
  int e0 = offs[node], e1 = offs[node + 1];
  for (int idx = e0; idx < e1; idx++) {
    int eid = csr[idx];
    int se = edge_index[eid];
    float rt = rel_t[eid];
    const unsigned short* ns = nodeout + (size_t)se * 768;
    uint4 kv = *(const uint4*)(ns + 128 + 8 * j);
    uint4 vv = *(const uint4*)(ns + 256 + 8 * j);
    float4 mg = *(const float4*)(edge_msg + (size_t)eid * 64 + 4 * j);
    float k0[4], k1[4], v0[4], v1[4];
    unpack8(kv, k0, k1); unpack8(vv, v0, v1);
    float cv[4];
    cv[0] = __cosf(rt * tw4.x + tb4.x);
    cv[1] = __cosf(rt * tw4.y + tb4.y);
    cv[2] = __cosf(rt * tw4.z + tb4.z);
    cv[3] = __cosf(rt * tw4.w + tb4.w);
    float p0 = q0[0] * k0[0] + q0[1] * k0[1] + q0[2] * k0[2] + q0[3] * k0[3]
             + qc0[0] * cv[0] + qc0[1] * cv[1] + qc0[2] * cv[2] + qc0[3] * cv[3]
             + qm0[0] * mg.x + qm0[1] * mg.y + qm0[2] * mg.z + qm0[3] * mg.w;
    float p1 = q1[0] * k1[0] + q1[1] * k1[1] + q1[2] * k1[2] + q1[3] * k1[3]
             + qc1[0] * cv[0] + qc1[1] * cv[1] + qc1[2] * cv[2] + qc1[3] * cv[3]
             + qm1[0] * mg.x + qm1[1] * mg.y + qm1[2] * mg.z + qm1[3] * mg.w;
    #pragma unroll
    for (int s = 1; s < 16; s <<= 1) { p0 += __shfl_xor(p0, s, 64); p1 += __shfl_xor(p1, s, 64); }
    float ex0 = __expf(p0 + qbe0), ex1 = __expf(p1 + qbe1);
    d0 += ex0; d1 += ex1;
    float mgc[4] = {mg.x, mg.y, mg.z, mg.w};
    #pragma unroll
    for (int c = 0; c < 4; c++) {
      aV0[c] += ex0 * v0[c]; aC0[c] += ex0 * cv[c]; aM0[c] += ex0 * mgc[c];
      aV1[c] += ex1 * v1[c]; aC1[c] += ex1 * cv[c]; aM1[c] += ex1 * mgc[c];
    }
  }
  float i0 = 1.f / (d0 + 1e-16f), i1 = 1.f / (d1 + 1e-16f);
  unsigned short* ag = aggbuf + (size_t)node * 512;
  *(ushort4*)(ag + 4 * j)       = pkv4(aV0[0] * i0, aV0[1] * i0, aV0[2] * i0, aV0[3] * i0);
  *(ushort4*)(ag + 64 + 4 * j)  = pkv4(aV1[0] * i1, aV1[1] * i1, aV1[2] * i1, aV1[3] * i1);
  *(ushort4*)(ag + 128 + 4 * j) = pkv4(aC0[0] * i0, aC0[1] * i0, aC0[2] * i0, aC0[3] * i0);
  *(ushort4*)(ag + 192 + 4 * j) = pkv4(aM0[0] * i0, aM0[1] * i0, aM0[2] * i0, aM0[3] * i0);
  *(ushort4*)(ag + 256 + 4 * j) = pkv4(aC1[0] * i1, aC1[1] * i1, aC1[2] * i1, aC1[3] * i1);
  *(ushort4*)(ag + 320 + 4 * j) = pkv4(aM1[0] * i1, aM1[1] * i1, aM1[2] * i1, aM1[3] * i1);
  *(uint4*)(ag + 384 + 8 * j)   = *(const uint4*)(nr + 384 + 8 * j);
  if (j == 0) { salph[node * 2] = d0 * i0; salph[node * 2 + 1] = d1 * i1; }
}

// ---- final GEMM: [65536,512] @ [512,64] bf16 MFMA -> h fp32 ---------------
__global__ __launch_bounds__(128)
void k_gemm_final(const unsigned short* __restrict__ aggbuf, const unsigned short* __restrict__ W2t,
                  const float* __restrict__ salph, const float* __restrict__ bem,
                  const float* __restrict__ mlp_b, float* __restrict__ h) {
  __shared__ unsigned short sA[128][LDK];
  __shared__ unsigned short sB[64][LDK];
  int t = threadIdx.x;
  int row0 = blockIdx.x * 128;
  int w = t >> 6, lane = t & 63, quad = lane >> 4, r16 = lane & 15;
  int m_off = w * 64;
  f32x4 acc[4][4] = {};
  for (int st = 0; st < 8; st++) {
    int ks = st * 64;
    __syncthreads();
    #pragma unroll
    for (int c = 0; c < 8; c++)
      *(uint4*)&sA[t][c * 8] = *(const uint4*)(aggbuf + (size_t)(row0 + t) * 512 + ks + c * 8);
    int brr = t >> 1;
    #pragma unroll
    for (int jj = 0; jj < 4; jj++) {
      int c = (t & 1) * 4 + jj;
      *(uint4*)&sB[brr][c * 8] = *(const uint4*)(W2t + (size_t)brr * 512 + ks + c * 8);
    }
    __syncthreads();
    #pragma unroll
    for (int kk = 0; kk < 2; kk++) {
      short8 af[4], bf_[4];
      #pragma unroll
      for (int i = 0; i < 4; i++) af[i]  = *(const short8*)&sA[m_off + i * 16 + r16][kk * 32 + quad * 8];
      #pragma unroll
      for (int i = 0; i < 4; i++) bf_[i] = *(const short8*)&sB[i * 16 + r16][kk * 32 + quad * 8];
      #pragma unroll
      for (int i = 0; i < 4; i++)
        #pragma unroll
        for (int jj = 0; jj < 4; jj++)
          acc[i][jj] = __builtin_amdgcn_mfma_f32_16x16x32_bf16(af[i], bf_[jj], acc[i][jj], 0, 0, 0);
    }
  }
  #pragma unroll
  for (int jj = 0; jj < 4; jj++) {
    int col = jj * 16 + r16;
    float mb = mlp_b[col], b0 = bem[col], b1 = bem[64 + col];
    #pragma unroll
    for (int i = 0; i < 4; i++) {
      int rbase = row0 + m_off + i * 16 + quad * 4;
      #pragma unroll
      for (int rg = 0; rg < 4; rg++) {
        int rr = rbase + rg;
        h[(size_t)rr * 64 + col] = acc[i][jj][rg] + mb + salph[rr * 2] * b0 + salph[rr * 2 + 1] * b1;
      }
    }
  }
}

__global__ __launch_bounds__(256)
void k_linkpred(const float* __restrict__ h, const int* __restrict__ assoc,
                const int* __restrict__ src, const int* __restrict__ dst,
                const int* __restrict__ neg, const float* __restrict__ lps_w,
                const float* __restrict__ lps_b, const float* __restrict__ lpd_w,
                const float* __restrict__ lpd_b, const float* __restrict__ lpf_w,
                const float* __restrict__ lpf_b, float* __restrict__ out) {
  int t = threadIdx.x, w = t >> 6, j = t & 63;
  int b = blockIdx.x * 4 + w;
  const float* hs = h + (size_t)assoc[src[b]] * 64;
  const float* hd = h + (size_t)assoc[dst[b]] * 64;
  const float* hn = h + (size_t)assoc[neg[b]] * 64;
  float vs = lps_b[j], vd = lpd_b[j], vn = lpd_b[j];
  for (int k = 0; k < 64; k++) {
    float ws_ = lps_w[k * 64 + j];
    float wd_ = lpd_w[k * 64 + j];
    vs += hs[k] * ws_;
    vd += hd[k] * wd_;
    vn += hn[k] * wd_;
  }
  float fw = lpf_w[j];
  float hp = fmaxf(vs + vd, 0.f) * fw;
  float hq = fmaxf(vs + vn, 0.f) * fw;
  #pragma unroll
  for (int m = 1; m < 64; m <<= 1) {
    hp += __shfl_xor(hp, m, 64);
    hq += __shfl_xor(hq, m, 64);
  }
  if (j == 0) {
    out[b] = hp + lpf_b[0];
    out[NBATCH + b] = hq + lpf_b[0];
  }
}

extern "C" void kernel_launch(void* const* d_in, const int* in_sizes, int n_in,
                              void* d_out, int out_size, void* d_ws, size_t ws_size,
                              hipStream_t stream) {
  if (n_in < 30) return;
  const float* memory      = (const float*)d_in[0];
  const float* pos_memory  = (const float*)d_in[1];
  const float* last_update = (const float*)d_in[2];
  const int*   n_id        = (const int*)d_in[3];
  const int*   edge_index  = (const int*)d_in[4];
  const float* edge_t      = (const float*)d_in[5];
  const float* edge_msg    = (const float*)d_in[6];
  const int*   src         = (const int*)d_in[7];
  const int*   dst         = (const int*)d_in[8];
  const int*   neg_dst     = (const int*)d_in[9];
  const float* time_w      = (const float*)d_in[10];
  const float* time_b      = (const float*)d_in[11];
  const float* Wq = (const float*)d_in[12]; const float* bq = (const float*)d_in[13];
  const float* Wk = (const float*)d_in[14]; const float* bk = (const float*)d_in[15];
  const float* Wv = (const float*)d_in[16]; const float* bv = (const float*)d_in[17];
  const float* We = (const float*)d_in[18]; const float* be = (const float*)d_in[19];
  const float* Wskip = (const float*)d_in[20]; const float* bskip = (const float*)d_in[21];
  const float* mlp_w = (const float*)d_in[22]; const float* mlp_b = (const float*)d_in[23];
  const float* lps_w = (const float*)d_in[24]; const float* lps_b = (const float*)d_in[25];
  const float* lpd_w = (const float*)d_in[26]; const float* lpd_b = (const float*)d_in[27];
  const float* lpf_w = (const float*)d_in[28]; const float* lpf_b = (const float*)d_in[29];
  float* out = (float*)d_out;

  char* ws = (char*)d_ws;
  size_t off = 0;
  auto alloc = [&](size_t bytes) -> void* {
    void* p = ws + off;
    off += (bytes + 255) & ~(size_t)255;
    return p;
  };
  int*   assoc   = (int*)alloc((size_t)NNODES * 4);
  unsigned short* Wt  = (unsigned short*)alloc((size_t)768 * 256 * 2);
  float* bias    = (float*)alloc(768 * 4);
  unsigned short* W2t = (unsigned short*)alloc((size_t)64 * 512 * 2);
  float* bem     = (float*)alloc(128 * 4);
  float* rel_t   = (float*)alloc((size_t)NEDGE * 4);
  unsigned short* anodes  = (unsigned short*)alloc((size_t)NSUB * 256 * 2);
  unsigned short* nodeout = (unsigned short*)alloc((size_t)NSUB * 768 * 2);
  unsigned short* aggbuf  = (unsigned short*)alloc((size_t)NSUB * 512 * 2);
  float* salph   = (float*)alloc((size_t)NSUB * 2 * 4);
  int*   deg     = (int*)alloc((size_t)NSUB * 4);
  int*   offs    = (int*)alloc((size_t)(NSUB + 1) * 4);
  int*   cursor  = (int*)alloc((size_t)(NSUB + 1) * 4);
  int*   csr     = (int*)alloc((size_t)NEDGE * 4);
  float* hbuf    = (float*)alloc((size_t)NSUB * 64 * 4);

  if (ws_size < off) {
    k_sentinel<<<1, 1, 0, stream>>>(out);
    return;
  }

  (void)hipMemsetAsync(deg, 0, (size_t)NSUB * 4, stream);
  k_packW<<<768, 256, 0, stream>>>(Wq, bq, Wk, bk, Wv, bv, Wskip, bskip, We, Wt, bias);
  k_packW2<<<512, 64, 0, stream>>>(We, mlp_w, W2t);
  k_bem<<<2, 64, 0, stream>>>(be, mlp_w, bem);
  k_assoc<<<NSUB / 256, 256, 0, stream>>>(n_id, assoc);
  k_packA<<<NSUB * 32 / 256, 256, 0, stream>>>(memory, pos_memory, n_id, anodes);
  k_prep_edge<<<NEDGE / 256, 256, 0, stream>>>(edge_index, n_id, last_update, edge_t, rel_t, deg);
  k_scan<<<1, 1024, 0, stream>>>(deg, offs, cursor);
  k_scatter<<<NEDGE / 256, 256, 0, stream>>>(edge_index, cursor, csr);
  k_gemm_node<<<dim3(NSUB / 128, 6), 256, 0, stream>>>(anodes, Wt, bias, nodeout);
  k_edge<<<NSUB / 16, 256, 0, stream>>>(nodeout, edge_index, rel_t, edge_msg, time_w, time_b,
                                        be, offs, csr, aggbuf, salph);
  k_gemm_final<<<NSUB / 128, 128, 0, stream>>>(aggbuf, W2t, salph, bem, mlp_b, hbuf);
  k_linkpred<<<NBATCH / 4, 256, 0, stream>>>(hbuf, assoc, src, dst, neg_dst,
                                             lps_w, lps_b, lpd_w, lpd_b, lpf_w, lpf_b, out);
}

// Round 5
// 698.655 us; speedup vs baseline: 1.9084x; 1.0615x over previous
//
#include <hip/hip_runtime.h>
#include <math.h>

#define NNODES 100000
#define NSUB   65536
#define NEDGE  655360
#define NBATCH 4096
#define LDK 72   // LDS k-stride (elements): 144B, 16B-aligned rows, 2-way conflicts only

typedef __attribute__((ext_vector_type(8))) short short8;
typedef __attribute__((ext_vector_type(4))) float f32x4;

__device__ __forceinline__ unsigned short f2bf(float x) {
  unsigned int b = __float_as_uint(x);
  b += 0x7fffu + ((b >> 16) & 1u);           // RNE
  return (unsigned short)(b >> 16);
}
__device__ __forceinline__ float bf2f(unsigned short u) {
  return __uint_as_float(((unsigned int)u) << 16);
}
__device__ __forceinline__ float bflo(unsigned int u) { return __uint_as_float(u << 16); }
__device__ __forceinline__ float bfhi(unsigned int u) { return __uint_as_float(u & 0xffff0000u); }
__device__ __forceinline__ unsigned int pk2(float a, float b) {
  return (unsigned int)f2bf(a) | ((unsigned int)f2bf(b) << 16);
}
__device__ __forceinline__ void unpack8(uint4 u, float* a, float* b) {
  a[0] = bflo(u.x); b[0] = bfhi(u.x);
  a[1] = bflo(u.y); b[1] = bfhi(u.y);
  a[2] = bflo(u.z); b[2] = bfhi(u.z);
  a[3] = bflo(u.w); b[3] = bfhi(u.w);
}
__device__ __forceinline__ ushort4 pkv4(float a, float b, float c, float d) {
  return make_ushort4(f2bf(a), f2bf(b), f2bf(c), f2bf(d));
}

__global__ void k_sentinel(float* out) { out[0] = -12345.0f; }

// ---- weight packing -------------------------------------------------------
// Wt[768][256] bf16, n-major. Column layout (== nodeout row layout):
// [0:128) q ilv (2l+h) *1/8 | [128:256) k ilv | [256:384) v ilv | [384:512) skip
// [512:640) qWe-cos ilv *1/8 | [640:768) qWe-msg ilv *1/8
__global__ void k_packW(const float* __restrict__ Wq, const float* __restrict__ bq,
                        const float* __restrict__ Wk, const float* __restrict__ bk,
                        const float* __restrict__ Wv, const float* __restrict__ bv,
                        const float* __restrict__ Ws, const float* __restrict__ bs,
                        const float* __restrict__ We,
                        unsigned short* __restrict__ Wt, float* __restrict__ bias) {
  int n = blockIdx.x, r = threadIdx.x;   // n<768, r<256
  float v = 0.f, bn = 0.f;
  if (n < 128) {
    int l = n >> 1, h = n & 1;
    v = Wq[r * 128 + h * 64 + l] * 0.125f; bn = bq[h * 64 + l] * 0.125f;
  } else if (n < 256) {
    int i = n - 128, l = i >> 1, h = i & 1;
    v = Wk[r * 128 + h * 64 + l]; bn = bk[h * 64 + l];
  } else if (n < 384) {
    int i = n - 256, l = i >> 1, h = i & 1;
    v = Wv[r * 128 + h * 64 + l]; bn = bv[h * 64 + l];
  } else if (n < 512) {
    int c = n - 384; v = Ws[r * 128 + c]; bn = bs[c];
  } else {
    int i = (n < 640) ? (n - 512) : (n - 640);
    int c = i >> 1, h = i & 1;
    int kk = (n < 640) ? c : (64 + c);
    float s = 0.f;
    for (int d = 0; d < 64; d++) s += Wq[r * 128 + h * 64 + d] * We[kk * 128 + h * 64 + d];
    v = s * 0.125f;
    if (r == 0) {
      float sb = 0.f;
      for (int d = 0; d < 64; d++) sb += bq[h * 64 + d] * We[kk * 128 + h * 64 + d];
      bn = sb * 0.125f;
    }
  }
  Wt[(size_t)n * 256 + r] = f2bf(v);
  if (r == 0) bias[n] = bn;
}

// W2t[64][512] bf16: cols of A2 = [aggV(128) | cos0 msg0 cos1 msg1 (256) | skip(128)]
__global__ void k_packW2(const float* __restrict__ We, const float* __restrict__ mlp_w,
                         unsigned short* __restrict__ W2t) {
  int r = blockIdx.x, j = threadIdx.x;   // r<512, j<64
  float v;
  if (r < 128) v = mlp_w[r * 64 + j];
  else if (r < 192) { int k = r - 128; float s = 0; for (int c = 0; c < 64; c++) s += We[k * 128 + c] * mlp_w[c * 64 + j]; v = s; }
  else if (r < 256) { int k = r - 192; float s = 0; for (int c = 0; c < 64; c++) s += We[(64 + k) * 128 + c] * mlp_w[c * 64 + j]; v = s; }
  else if (r < 320) { int k = r - 256; float s = 0; for (int c = 0; c < 64; c++) s += We[k * 128 + 64 + c] * mlp_w[(64 + c) * 64 + j]; v = s; }
  else if (r < 384) { int k = r - 320; float s = 0; for (int c = 0; c < 64; c++) s += We[(64 + k) * 128 + 64 + c] * mlp_w[(64 + c) * 64 + j]; v = s; }
  else v = mlp_w[(r - 384) * 64 + j];
  W2t[(size_t)j * 512 + r] = f2bf(v);
}

__global__ void k_bem(const float* __restrict__ be, const float* __restrict__ mlp_w,
                      float* __restrict__ bem) {
  int h = blockIdx.x, j = threadIdx.x;
  float s = 0.f;
  for (int c = 0; c < 64; c++) s += be[h * 64 + c] * mlp_w[(h * 64 + c) * 64 + j];
  bem[h * 64 + j] = s;
}

// ---- prep ----------------------------------------------------------------
__global__ void k_assoc(const int* __restrict__ n_id, int* __restrict__ assoc) {
  int i = blockIdx.x * 256 + threadIdx.x;
  if (i < NSUB) assoc[n_id[i]] = i;
}

// anodes[NSUB][256] bf16 = concat(memory,pos_memory)[n_id]
__global__ void k_packA(const float* __restrict__ mem, const float* __restrict__ pmem,
                        const int* __restrict__ n_id, unsigned short* __restrict__ anodes) {
  int i = blockIdx.x * 256 + threadIdx.x;   // 8-elem chunk index
  int node = i >> 5, ch = i & 31;
  int nid = n_id[node];
  const float* src = (ch < 16) ? (mem + (size_t)nid * 128 + ch * 8)
                               : (pmem + (size_t)nid * 128 + (ch - 16) * 8);
  float4 f0 = *(const float4*)src, f1 = *(const float4*)(src + 4);
  uint4 o;
  o.x = pk2(f0.x, f0.y); o.y = pk2(f0.z, f0.w);
  o.z = pk2(f1.x, f1.y); o.w = pk2(f1.z, f1.w);
  *(uint4*)(anodes + (size_t)node * 256 + ch * 8) = o;
}

__global__ void k_prep_edge(const int* __restrict__ edge_index, const int* __restrict__ n_id,
                            const float* __restrict__ last_update, const float* __restrict__ edge_t,
                            float* __restrict__ rel_t, int* __restrict__ deg) {
  int e = blockIdx.x * 256 + threadIdx.x;
  if (e < NEDGE) {
    rel_t[e] = last_update[n_id[edge_index[e]]] - edge_t[e];
    atomicAdd(&deg[edge_index[NEDGE + e]], 1);
  }
}

// edge_msg fp32 -> bf16, coalesced
__global__ void k_msgb(const float* __restrict__ edge_msg, unsigned int* __restrict__ msgb) {
  int i = blockIdx.x * 256 + threadIdx.x;   // i < NEDGE*32
  float2 f = *(const float2*)(edge_msg + (size_t)i * 2);
  msgb[i] = pk2(f.x, f.y);
}

// ---- parallel 3-phase exclusive scan over deg[NSUB] -----------------------
__global__ __launch_bounds__(1024)
void k_scan1(const int* __restrict__ deg, int* __restrict__ excl, int* __restrict__ btot) {
  __shared__ int wsum[16];
  int t = threadIdx.x, w = t >> 6, l = t & 63;
  int i = blockIdx.x * 1024 + t;
  int v = deg[i], s = v;
  #pragma unroll
  for (int d = 1; d < 64; d <<= 1) { int u = __shfl_up(s, d, 64); if (l >= d) s += u; }
  if (l == 63) wsum[w] = s;
  __syncthreads();
  int woff = 0;
  #pragma unroll
  for (int k = 0; k < 16; k++) woff += (k < w) ? wsum[k] : 0;
  excl[i] = woff + s - v;
  if (t == 1023) btot[blockIdx.x] = woff + s;
}

__global__ void k_scan2(const int* __restrict__ btot, int* __restrict__ boff,
                        int* __restrict__ offs, int* __restrict__ cursor) {
  int l = threadIdx.x;   // 64
  int v = btot[l], s = v;
  #pragma unroll
  for (int d = 1; d < 64; d <<= 1) { int u = __shfl_up(s, d, 64); if (l >= d) s += u; }
  boff[l] = s - v;
  if (l == 63) { offs[NSUB] = s; cursor[NSUB] = s; }
}

__global__ __launch_bounds__(1024)
void k_scan3(const int* __restrict__ excl, const int* __restrict__ boff,
             int* __restrict__ offs, int* __restrict__ cursor) {
  int i = blockIdx.x * 1024 + threadIdx.x;
  int o = excl[i] + boff[blockIdx.x];
  offs[i] = o; cursor[i] = o;
}

// csrmeta[p] = {se, rel_t bits, eid, 0} in CSR (dst-grouped) order
__global__ void k_scatter(const int* __restrict__ edge_index, const float* __restrict__ rel_t,
                          int* __restrict__ cursor, uint4* __restrict__ csrmeta) {
  int e = blockIdx.x * 256 + threadIdx.x;
  if (e < NEDGE) {
    int de = edge_index[NEDGE + e];
    int p = atomicAdd(&cursor[de], 1);
    csrmeta[p] = make_uint4((unsigned)edge_index[e], __float_as_uint(rel_t[e]), (unsigned)e, 0u);
  }
}

// ---- node GEMM: [65536,256] @ [256,768] bf16 MFMA -> nodeout bf16 ---------
__global__ __launch_bounds__(256)
void k_gemm_node(const unsigned short* __restrict__ anodes, const unsigned short* __restrict__ Wt,
                 const float* __restrict__ bias, unsigned short* __restrict__ nodeout) {
  __shared__ unsigned short sA[128][LDK];
  __shared__ unsigned short sB[128][LDK];
  int t = threadIdx.x;
  int row0 = blockIdx.x * 128, n0 = blockIdx.y * 128;
  int ar = t >> 1, ak = (t & 1) * 32;
  int w = t >> 6, lane = t & 63, quad = lane >> 4, r16 = lane & 15;
  int m_off = (w >> 1) * 64, n_off = (w & 1) * 64;
  f32x4 acc[4][4] = {};
  for (int st = 0; st < 4; st++) {
    int ks = st * 64;
    __syncthreads();
    #pragma unroll
    for (int i = 0; i < 4; i++)
      *(uint4*)&sA[ar][ak + i * 8] = *(const uint4*)(anodes + (size_t)(row0 + ar) * 256 + ks + ak + i * 8);
    #pragma unroll
    for (int i = 0; i < 4; i++)
      *(uint4*)&sB[ar][ak + i * 8] = *(const uint4*)(Wt + (size_t)(n0 + ar) * 256 + ks + ak + i * 8);
    __syncthreads();
    #pragma unroll
    for (int kk = 0; kk < 2; kk++) {
      short8 af[4], bf_[4];
      #pragma unroll
      for (int i = 0; i < 4; i++) af[i]  = *(const short8*)&sA[m_off + i * 16 + r16][kk * 32 + quad * 8];
      #pragma unroll
      for (int i = 0; i < 4; i++) bf_[i] = *(const short8*)&sB[n_off + i * 16 + r16][kk * 32 + quad * 8];
      #pragma unroll
      for (int i = 0; i < 4; i++)
        #pragma unroll
        for (int j = 0; j < 4; j++)
          acc[i][j] = __builtin_amdgcn_mfma_f32_16x16x32_bf16(af[i], bf_[j], acc[i][j], 0, 0, 0);
    }
  }
  #pragma unroll
  for (int j = 0; j < 4; j++) {
    int col = n0 + n_off + j * 16 + r16;
    float bv_ = bias[col];
    #pragma unroll
    for (int i = 0; i < 4; i++) {
      int rbase = row0 + m_off + i * 16 + quad * 4;
      #pragma unroll
      for (int rg = 0; rg < 4; rg++)
        nodeout[(size_t)(rbase + rg) * 768 + col] = f2bf(acc[i][j][rg] + bv_);
    }
  }
}

// ---- fused edge pass: 16-lane group per dest node, chunk-16 meta prefetch -
__global__ __launch_bounds__(256)
void k_edge(const unsigned short* __restrict__ nodeout, const unsigned short* __restrict__ msgb,
            const float* __restrict__ time_w, const float* __restrict__ time_b,
            const float* __restrict__ be, const int* __restrict__ offs,
            const uint4* __restrict__ csrmeta, unsigned short* __restrict__ aggbuf,
            float* __restrict__ salph) {
  int t = threadIdx.x, w = t >> 6, lane = t & 63;
  int j = lane & 15;
  int node = blockIdx.x * 16 + w * 4 + (lane >> 4);
  const unsigned short* nr = nodeout + (size_t)node * 768;
  uint4 q4  = *(const uint4*)(nr + 8 * j);
  uint4 qc4 = *(const uint4*)(nr + 512 + 8 * j);
  uint4 qm4 = *(const uint4*)(nr + 640 + 8 * j);
  float4 tw4 = *(const float4*)(time_w + 4 * j);
  float4 tb4 = *(const float4*)(time_b + 4 * j);
  float4 beA = *(const float4*)(be + 4 * j);
  float4 beB = *(const float4*)(be + 64 + 4 * j);
  float q0[4], q1[4], qc0[4], qc1[4], qm0[4], qm1[4];
  unpack8(q4, q0, q1); unpack8(qc4, qc0, qc1); unpack8(qm4, qm0, qm1);
  float qbe0 = q0[0] * beA.x + q0[1] * beA.y + q0[2] * beA.z + q0[3] * beA.w;
  float qbe1 = q1[0] * beB.x + q1[1] * beB.y + q1[2] * beB.z + q1[3] * beB.w;
  #pragma unroll
  for (int s = 1; s < 16; s <<= 1) { qbe0 += __shfl_xor(qbe0, s, 64); qbe1 += __shfl_xor(qbe1, s, 64); }
  float d0 = 0.f, d1 = 0.f;
  float aV0[4] = {}, aV1[4] = {}, aC0[4] = {}, aC1[4] = {}, aM0[4] = {}, aM1[4] = {};
  int e0 = offs[node], e1 = offs[node + 1];
  int deg = e1 - e0;
  int lb = lane & 48;
  for (int base = 0; base < deg; base += 16) {
    int cidx = e0 + base + j;
    int hi = e1 - 1;
    cidx = cidx > hi ? hi : cidx;
    uint4 mt = csrmeta[cidx];                  // one coalesced 256B meta load / group
    int rem = deg - base; rem = rem > 16 ? 16 : rem;
    for (int c = 0; c < rem; c += 4) {
      uint4 kvr[4], vvr[4];
      uint2 mgr[4];
      float rtv[4];
      #pragma unroll
      for (int ii = 0; ii < 4; ii++) {
        int sl = lb | (c + ii);
        int se_i = __shfl((int)mt.x, sl, 64);
        rtv[ii] = __uint_as_float((unsigned)__shfl((int)mt.y, sl, 64));
        int eid_i = __shfl((int)mt.z, sl, 64);
        const unsigned short* ns = nodeout + (size_t)se_i * 768;
        kvr[ii] = *(const uint4*)(ns + 128 + 8 * j);
        vvr[ii] = *(const uint4*)(ns + 256 + 8 * j);
        mgr[ii] = *(const uint2*)(msgb + (size_t)eid_i * 64 + 4 * j);
      }
      #pragma unroll
      for (int ii = 0; ii < 4; ii++) {
        float msk = (c + ii < rem) ? 1.f : 0.f;
        float k0[4], k1[4], v0[4], v1[4];
        unpack8(kvr[ii], k0, k1); unpack8(vvr[ii], v0, v1);
        float mgc[4] = {bflo(mgr[ii].x), bfhi(mgr[ii].x), bflo(mgr[ii].y), bfhi(mgr[ii].y)};
        float rt = rtv[ii];
        float cv[4];
        cv[0] = __cosf(rt * tw4.x + tb4.x);
        cv[1] = __cosf(rt * tw4.y + tb4.y);
        cv[2] = __cosf(rt * tw4.z + tb4.z);
        cv[3] = __cosf(rt * tw4.w + tb4.w);
        float p0 = q0[0] * k0[0] + q0[1] * k0[1] + q0[2] * k0[2] + q0[3] * k0[3]
                 + qc0[0] * cv[0] + qc0[1] * cv[1] + qc0[2] * cv[2] + qc0[3] * cv[3]
                 + qm0[0] * mgc[0] + qm0[1] * mgc[1] + qm0[2] * mgc[2] + qm0[3] * mgc[3];
        float p1 = q1[0] * k1[0] + q1[1] * k1[1] + q1[2] * k1[2] + q1[3] * k1[3]
                 + qc1[0] * cv[0] + qc1[1] * cv[1] + qc1[2] * cv[2] + qc1[3] * cv[3]
                 + qm1[0] * mgc[0] + qm1[1] * mgc[1] + qm1[2] * mgc[2] + qm1[3] * mgc[3];
        #pragma unroll
        for (int s = 1; s < 16; s <<= 1) { p0 += __shfl_xor(p0, s, 64); p1 += __shfl_xor(p1, s, 64); }
        float ex0 = __expf(p0 + qbe0) * msk, ex1 = __expf(p1 + qbe1) * msk;
        d0 += ex0; d1 += ex1;
        #pragma unroll
        for (int cc = 0; cc < 4; cc++) {
          aV0[cc] += ex0 * v0[cc]; aC0[cc] += ex0 * cv[cc]; aM0[cc] += ex0 * mgc[cc];
          aV1[cc] += ex1 * v1[cc]; aC1[cc] += ex1 * cv[cc]; aM1[cc] += ex1 * mgc[cc];
        }
      }
    }
  }
  float i0 = 1.f / (d0 + 1e-16f), i1 = 1.f / (d1 + 1e-16f);
  unsigned short* ag = aggbuf + (size_t)node * 512;
  *(ushort4*)(ag + 4 * j)       = pkv4(aV0[0] * i0, aV0[1] * i0, aV0[2] * i0, aV0[3] * i0);
  *(ushort4*)(ag + 64 + 4 * j)  = pkv4(aV1[0] * i1, aV1[1] * i1, aV1[2] * i1, aV1[3] * i1);
  *(ushort4*)(ag + 128 + 4 * j) = pkv4(aC0[0] * i0, aC0[1] * i0, aC0[2] * i0, aC0[3] * i0);
  *(ushort4*)(ag + 192 + 4 * j) = pkv4(aM0[0] * i0, aM0[1] * i0, aM0[2] * i0, aM0[3] * i0);
  *(ushort4*)(ag + 256 + 4 * j) = pkv4(aC1[0] * i1, aC1[1] * i1, aC1[2] * i1, aC1[3] * i1);
  *(ushort4*)(ag + 320 + 4 * j) = pkv4(aM1[0] * i1, aM1[1] * i1, aM1[2] * i1, aM1[3] * i1);
  *(uint4*)(ag + 384 + 8 * j)   = *(const uint4*)(nr + 384 + 8 * j);
  if (j == 0) { salph[node * 2] = d0 * i0; salph[node * 2 + 1] = d1 * i1; }
}

// ---- final GEMM: [65536,512] @ [512,64] bf16 MFMA -> h fp32 ---------------
__global__ __launch_bounds__(128)
void k_gemm_final(const unsigned short* __restrict__ aggbuf, const unsigned short* __restrict__ W2t,
                  const float* __restrict__ salph, const float* __restrict__ bem,
                  const float* __restrict__ mlp_b, float* __restrict__ h) {
  __shared__ unsigned short sA[128][LDK];
  __shared__ unsigned short sB[64][LDK];
  int t = threadIdx.x;
  int row0 = blockIdx.x * 128;
  int w = t >> 6, lane = t & 63, quad = lane >> 4, r16 = lane & 15;
  int m_off = w * 64;
  f32x4 acc[4][4] = {};
  for (int st = 0; st < 8; st++) {
    int ks = st * 64;
    __syncthreads();
    #pragma unroll
    for (int c = 0; c < 8; c++)
      *(uint4*)&sA[t][c * 8] = *(const uint4*)(aggbuf + (size_t)(row0 + t) * 512 + ks + c * 8);
    int brr = t >> 1;
    #pragma unroll
    for (int jj = 0; jj < 4; jj++) {
      int c = (t & 1) * 4 + jj;
      *(uint4*)&sB[brr][c * 8] = *(const uint4*)(W2t + (size_t)brr * 512 + ks + c * 8);
    }
    __syncthreads();
    #pragma unroll
    for (int kk = 0; kk < 2; kk++) {
      short8 af[4], bf_[4];
      #pragma unroll
      for (int i = 0; i < 4; i++) af[i]  = *(const short8*)&sA[m_off + i * 16 + r16][kk * 32 + quad * 8];
      #pragma unroll
      for (int i = 0; i < 4; i++) bf_[i] = *(const short8*)&sB[i * 16 + r16][kk * 32 + quad * 8];
      #pragma unroll
      for (int i = 0; i < 4; i++)
        #pragma unroll
        for (int jj = 0; jj < 4; jj++)
          acc[i][jj] = __builtin_amdgcn_mfma_f32_16x16x32_bf16(af[i], bf_[jj], acc[i][jj], 0, 0, 0);
    }
  }
  #pragma unroll
  for (int jj = 0; jj < 4; jj++) {
    int col = jj * 16 + r16;
    float mb = mlp_b[col], b0 = bem[col], b1 = bem[64 + col];
    #pragma unroll
    for (int i = 0; i < 4; i++) {
      int rbase = row0 + m_off + i * 16 + quad * 4;
      #pragma unroll
      for (int rg = 0; rg < 4; rg++) {
        int rr = rbase + rg;
        h[(size_t)rr * 64 + col] = acc[i][jj][rg] + mb + salph[rr * 2] * b0 + salph[rr * 2 + 1] * b1;
      }
    }
  }
}

__global__ __launch_bounds__(256)
void k_linkpred(const float* __restrict__ h, const int* __restrict__ assoc,
                const int* __restrict__ src, const int* __restrict__ dst,
                const int* __restrict__ neg, const float* __restrict__ lps_w,
                const float* __restrict__ lps_b, const float* __restrict__ lpd_w,
                const float* __restrict__ lpd_b, const float* __restrict__ lpf_w,
                const float* __restrict__ lpf_b, float* __restrict__ out) {
  int t = threadIdx.x, w = t >> 6, j = t & 63;
  int b = blockIdx.x * 4 + w;
  const float* hs = h + (size_t)assoc[src[b]] * 64;
  const float* hd = h + (size_t)assoc[dst[b]] * 64;
  const float* hn = h + (size_t)assoc[neg[b]] * 64;
  float vs = lps_b[j], vd = lpd_b[j], vn = lpd_b[j];
  for (int k = 0; k < 64; k++) {
    float ws_ = lps_w[k * 64 + j];
    float wd_ = lpd_w[k * 64 + j];
    vs += hs[k] * ws_;
    vd += hd[k] * wd_;
    vn += hn[k] * wd_;
  }
  float fw = lpf_w[j];
  float hp = fmaxf(vs + vd, 0.f) * fw;
  float hq = fmaxf(vs + vn, 0.f) * fw;
  #pragma unroll
  for (int m = 1; m < 64; m <<= 1) {
    hp += __shfl_xor(hp, m, 64);
    hq += __shfl_xor(hq, m, 64);
  }
  if (j == 0) {
    out[b] = hp + lpf_b[0];
    out[NBATCH + b] = hq + lpf_b[0];
  }
}

extern "C" void kernel_launch(void* const* d_in, const int* in_sizes, int n_in,
                              void* d_out, int out_size, void* d_ws, size_t ws_size,
                              hipStream_t stream) {
  if (n_in < 30) return;
  const float* memory      = (const float*)d_in[0];
  const float* pos_memory  = (const float*)d_in[1];
  const float* last_update = (const float*)d_in[2];
  const int*   n_id        = (const int*)d_in[3];
  const int*   edge_index  = (const int*)d_in[4];
  const float* edge_t      = (const float*)d_in[5];
  const float* edge_msg    = (const float*)d_in[6];
  const int*   src         = (const int*)d_in[7];
  const int*   dst         = (const int*)d_in[8];
  const int*   neg_dst     = (const int*)d_in[9];
  const float* time_w      = (const float*)d_in[10];
  const float* time_b      = (const float*)d_in[11];
  const float* Wq = (const float*)d_in[12]; const float* bq = (const float*)d_in[13];
  const float* Wk = (const float*)d_in[14]; const float* bk = (const float*)d_in[15];
  const float* Wv = (const float*)d_in[16]; const float* bv = (const float*)d_in[17];
  const float* We = (const float*)d_in[18]; const float* be = (const float*)d_in[19];
  const float* Wskip = (const float*)d_in[20]; const float* bskip = (const float*)d_in[21];
  const float* mlp_w = (const float*)d_in[22]; const float* mlp_b = (const float*)d_in[23];
  const float* lps_w = (const float*)d_in[24]; const float* lps_b = (const float*)d_in[25];
  const float* lpd_w = (const float*)d_in[26]; const float* lpd_b = (const float*)d_in[27];
  const float* lpf_w = (const float*)d_in[28]; const float* lpf_b = (const float*)d_in[29];
  float* out = (float*)d_out;

  char* ws = (char*)d_ws;
  size_t off = 0;
  auto alloc = [&](size_t bytes) -> void* {
    void* p = ws + off;
    off += (bytes + 255) & ~(size_t)255;
    return p;
  };
  int*   assoc   = (int*)alloc((size_t)NNODES * 4);
  unsigned short* Wt  = (unsigned short*)alloc((size_t)768 * 256 * 2);
  float* bias    = (float*)alloc(768 * 4);
  unsigned short* W2t = (unsigned short*)alloc((size_t)64 * 512 * 2);
  float* bem     = (float*)alloc(128 * 4);
  float* rel_t   = (float*)alloc((size_t)NEDGE * 4);
  unsigned short* anodes  = (unsigned short*)alloc((size_t)NSUB * 256 * 2);
  unsigned short* nodeout = (unsigned short*)alloc((size_t)NSUB * 768 * 2);
  unsigned short* aggbuf  = (unsigned short*)alloc((size_t)NSUB * 512 * 2);
  float* salph   = (float*)alloc((size_t)NSUB * 2 * 4);
  int*   deg     = (int*)alloc((size_t)NSUB * 4);
  int*   offs    = (int*)alloc((size_t)(NSUB + 1) * 4);
  int*   cursor  = (int*)alloc((size_t)(NSUB + 1) * 4);
  int*   excl    = (int*)alloc((size_t)NSUB * 4);
  int*   btot    = (int*)alloc(64 * 4);
  int*   boff    = (int*)alloc(64 * 4);
  uint4* csrmeta = (uint4*)alloc((size_t)NEDGE * 16);
  unsigned int* msgb = (unsigned int*)alloc((size_t)NEDGE * 64 * 2);
  float* hbuf    = (float*)alloc((size_t)NSUB * 64 * 4);

  if (ws_size < off) {
    k_sentinel<<<1, 1, 0, stream>>>(out);
    return;
  }

  (void)hipMemsetAsync(deg, 0, (size_t)NSUB * 4, stream);
  k_packW<<<768, 256, 0, stream>>>(Wq, bq, Wk, bk, Wv, bv, Wskip, bskip, We, Wt, bias);
  k_packW2<<<512, 64, 0, stream>>>(We, mlp_w, W2t);
  k_bem<<<2, 64, 0, stream>>>(be, mlp_w, bem);
  k_assoc<<<NSUB / 256, 256, 0, stream>>>(n_id, assoc);
  k_packA<<<NSUB * 32 / 256, 256, 0, stream>>>(memory, pos_memory, n_id, anodes);
  k_prep_edge<<<NEDGE / 256, 256, 0, stream>>>(edge_index, n_id, last_update, edge_t, rel_t, deg);
  k_msgb<<<NEDGE * 32 / 256, 256, 0, stream>>>(edge_msg, msgb);
  k_scan1<<<NSUB / 1024, 1024, 0, stream>>>(deg, excl, btot);
  k_scan2<<<1, 64, 0, stream>>>(btot, boff, offs, cursor);
  k_scan3<<<NSUB / 1024, 1024, 0, stream>>>(excl, boff, offs, cursor);
  k_scatter<<<NEDGE / 256, 256, 0, stream>>>(edge_index, rel_t, cursor, csrmeta);
  k_gemm_node<<<dim3(NSUB / 128, 6), 256, 0, stream>>>(anodes, Wt, bias, nodeout);
  k_edge<<<NSUB / 16, 256, 0, stream>>>(nodeout, (const unsigned short*)msgb, time_w, time_b,
                                        be, offs, csrmeta, aggbuf, salph);
  k_gemm_final<<<NSUB / 128, 128, 0, stream>>>(aggbuf, W2t, salph, bem, mlp_b, hbuf);
  k_linkpred<<<NBATCH / 4, 256, 0, stream>>>(hbuf, assoc, src, dst, neg_dst,
                                             lps_w, lps_b, lpd_w, lpd_b, lpf_w, lpf_b, out);
}